// Round 1
// baseline (910.341 us; speedup 1.0000x reference)
//
#include <hip/hip_runtime.h>
#include <stdint.h>

#define NROWS   1024
#define NV      100000
#define NSEL    101           // K+1
#define NBINS   2048          // 11-bit sortable-float bins
#define POOLSZ  2048
#define CHUNK   1024          // 256 threads x 1 float4
#define NCHUNK  ((NV + CHUNK - 1) / CHUNK)   // 98

__device__ __forceinline__ uint32_t rotl32(uint32_t x, uint32_t r) {
  return (x << r) | (x >> (32u - r));
}

// JAX threefry2x32, partitionable path (default since jax 0.4.30):
// bits(n) = o0 ^ o1 of threefry2x32(key=(0,42), counts=(hi=0, lo=n)).
// ks = [0, 42, 0x1BD11BDA ^ 0 ^ 42 = 0x1BD11BF0]. Must be bit-exact.
__device__ __forceinline__ uint32_t jax_random_bits(uint32_t n) {
  const uint32_t K1 = 42u;
  const uint32_t K2 = 0x1BD11BF0u;
  uint32_t x0 = 0u;        // counts_hi(0) + ks[0](0)
  uint32_t x1 = n + K1;    // counts_lo + ks[1]
#define TF_R(r) { x0 += x1; x1 = rotl32(x1, (r)); x1 ^= x0; }
  TF_R(13u) TF_R(15u) TF_R(26u) TF_R(6u)
  x0 += K1; x1 += K2 + 1u;
  TF_R(17u) TF_R(29u) TF_R(16u) TF_R(24u)
  x0 += K2; x1 += 0u + 2u;
  TF_R(13u) TF_R(15u) TF_R(26u) TF_R(6u)
  x0 += 0u; x1 += K1 + 3u;
  TF_R(17u) TF_R(29u) TF_R(16u) TF_R(24u)
  x0 += K1; x1 += K2 + 4u;
  TF_R(13u) TF_R(15u) TF_R(26u) TF_R(6u)
  x0 += K2; x1 += 0u + 5u;
#undef TF_R
  return x0 ^ x1;
}

// JAX: uniform(minval=tiny, maxval=1): f = bitcast(bits>>9 | 0x3f800000)-1;
// u = max(tiny, f); gumbel = -log(-log(u)).  __logf (v_log_f32) accuracy
// (~1e-7 rel) only perturbs rank-boundary selection: negligible in the mean.
__device__ __forceinline__ float jax_gumbel(uint32_t n) {
  uint32_t bits = jax_random_bits(n);
  float f = __uint_as_float((bits >> 9) | 0x3f800000u) - 1.0f;
  f = fmaxf(f, 1.1754943508222875e-38f);
  return -__logf(-__logf(f));
}

// reduce across 256 threads; valid inputs padded with -inf (max) / 0 (sum)
__device__ __forceinline__ float blk_reduce(float x, int tid, float* wred, bool is_max) {
  #pragma unroll
  for (int off = 32; off >= 1; off >>= 1) {
    float o = __shfl_down(x, off);
    x = is_max ? fmaxf(x, o) : (x + o);
  }
  if ((tid & 63) == 0) wred[tid >> 6] = x;
  __syncthreads();
  float r;
  if (is_max) r = fmaxf(fmaxf(wred[0], wred[1]), fmaxf(wred[2], wred[3]));
  else        r = wred[0] + wred[1] + wred[2] + wred[3];
  __syncthreads();
  return r;
}

__device__ __forceinline__ uint32_t sortable_bin(float v) {
  uint32_t fb = __float_as_uint(v);
  uint32_t key = fb ^ (uint32_t)(((int32_t)fb >> 31) | (int32_t)0x80000000);
  return key >> 21;  // top 11 bits -> 2048 bins, monotone in v
}

__global__ void __launch_bounds__(256)
nce_row_kernel(const float* __restrict__ noise, const float* __restrict__ actual,
               const int* __restrict__ target, float* __restrict__ acc) {
  const int row = blockIdx.x;
  const int tid = threadIdx.x;

  __shared__ float    pv[POOLSZ];
  __shared__ uint32_t pi[POOLSZ];
  __shared__ uint32_t hist[NBINS];
  __shared__ uint32_t s_cnt;
  __shared__ uint32_t s_thr;
  __shared__ float    s_wred[4];

  for (int i = tid; i < NBINS; i += 256) hist[i] = 0u;
  if (tid == 0) { s_cnt = 0u; s_thr = 0u; }
  __syncthreads();

  const float* rowp = noise + (size_t)row * NV;
  const uint32_t tgt = (uint32_t)target[row];
  const uint32_t nbase = (uint32_t)row * (uint32_t)NV;  // < 2^32

  for (int c = 0; c < NCHUNK; ++c) {
    const uint32_t thr = s_thr;   // stale-low is safe (over-appends only)
    const int v = c * CHUNK + tid * 4;
    if (v < NV) {
      float4 a = *reinterpret_cast<const float4*>(rowp + v);
      float av[4] = {a.x, a.y, a.z, a.w};
      #pragma unroll
      for (int j = 0; j < 4; ++j) {
        const uint32_t col = (uint32_t)(v + j);
        // masked logit: target -> float32 finfo.min (stays finite after +g)
        const float logit = (col == tgt) ? -3.4028234663852886e+38f : av[j];
        const float val = logit + jax_gumbel(nbase + col);
        const uint32_t bin = sortable_bin(val);
        if (bin >= thr) {
          uint32_t pos = atomicAdd(&s_cnt, 1u);
          if (pos < POOLSZ) { pv[pos] = val; pi[pos] = col; }
          atomicAdd(&hist[bin], 1u);
        }
      }
    }
    __syncthreads();

    // wave 0: raise threshold = lowest bin with >=100 seen elements above it
    if (tid < 64) {
      const int bpl = NBINS / 64;           // 32 bins per lane
      uint32_t sum = 0;
      const uint32_t base = (uint32_t)tid * bpl;
      #pragma unroll
      for (int j = 0; j < bpl; ++j) sum += hist[base + j];
      uint32_t suf = sum;
      #pragma unroll
      for (int off = 1; off < 64; off <<= 1) {
        uint32_t o = __shfl_down(suf, off);
        if (tid + off < 64) suf += o;
      }
      const uint32_t sufnext = suf - sum;   // suffix starting at next lane
      if (suf >= 100u && sufnext < 100u) {
        uint32_t cum = sufnext;
        uint32_t b = base + bpl - 1;
        for (;; --b) { cum += hist[b]; if (cum >= 100u) break; }
        if (b > s_thr) s_thr = b;           // single writer lane
      }
    }
    __syncthreads();

    // compact pool when it could overflow next chunk
    if (s_cnt > (uint32_t)(POOLSZ - CHUNK)) {
      const uint32_t n = min(s_cnt, (uint32_t)POOLSZ);
      const uint32_t thr2 = s_thr;
      float    lv[8]; uint32_t li[8]; int nkeep = 0;
      for (uint32_t p = tid; p < n; p += 256) {
        float val = pv[p];
        if (sortable_bin(val) >= thr2) { lv[nkeep] = val; li[nkeep] = pi[p]; ++nkeep; }
      }
      __syncthreads();
      if (tid == 0) s_cnt = 0u;
      __syncthreads();
      for (int k = 0; k < nkeep; ++k) {
        uint32_t pos = atomicAdd(&s_cnt, 1u);
        if (pos < POOLSZ) { pv[pos] = lv[k]; pi[pos] = li[k]; }
      }
      __syncthreads();
    }
  }
  __syncthreads();

  // ---- final exact top-100, sorted desc by (val, then idx asc) ----
  const uint32_t n = min(s_cnt, (uint32_t)POOLSZ);   // >= 100 guaranteed
  uint32_t sortn = 128;
  while (sortn < n) sortn <<= 1;                     // <= 2048
  for (uint32_t i = n + tid; i < sortn; i += 256) { pv[i] = -INFINITY; pi[i] = 0xFFFFFFFFu; }
  __syncthreads();

  for (uint32_t ksz = 2; ksz <= sortn; ksz <<= 1) {
    for (uint32_t jsz = ksz >> 1; jsz >= 1; jsz >>= 1) {
      for (uint32_t i = tid; i < sortn; i += 256) {
        const uint32_t ixj = i ^ jsz;
        if (ixj > i) {
          const bool desc = ((i & ksz) == 0);
          float va = pv[i], vb = pv[ixj];
          uint32_t ia = pi[i], ib = pi[ixj];
          const bool a_less = (va < vb) || (va == vb && ia > ib);
          if (desc ? a_less : !a_less) {
            pv[i] = vb; pv[ixj] = va; pi[i] = ib; pi[ixj] = ia;
          }
        }
      }
      __syncthreads();
    }
  }

  // ---- scoring: softmax over gathered noise logits & actual logits ----
  float nl = -INFINITY, al = -INFINITY;
  if (tid < NSEL) {
    const uint32_t idx = (tid == 0) ? tgt : pi[tid - 1];
    nl = rowp[idx];                            // original (unmasked) logits
    al = actual[(size_t)row * NSEL + tid];
  }
  const float mn = blk_reduce(nl, tid, s_wred, true);
  const float ma = blk_reduce(al, tid, s_wred, true);
  const float en = (tid < NSEL) ? __expf(nl - mn) : 0.0f;
  const float ea = (tid < NSEL) ? __expf(al - ma) : 0.0f;
  const float sn = blk_reduce(en, tid, s_wred, false);
  const float sa = blk_reduce(ea, tid, s_wred, false);

  float contrib = 0.0f;
  if (tid < NSEL) {
    const float npj = en / sn;
    const float apj = ea / sa;
    const float deno = 100.0f * npj + apj + 1e-6f;
    float t = (tid == 0) ? (apj / deno) : (npj / deno);
    if (t == 1.0f) t = 1.0f + 1e-6f;           // exact reference quirk
    contrib = logf(t);
  }
  const float tot = blk_reduce(contrib, tid, s_wred, false);
  if (tid == 0) atomicAdd(acc, tot);
}

__global__ void zero_acc_kernel(float* acc) {
  if (threadIdx.x == 0 && blockIdx.x == 0) acc[0] = 0.0f;
}

__global__ void finalize_kernel(const float* __restrict__ acc, float* __restrict__ out) {
  if (threadIdx.x == 0 && blockIdx.x == 0)
    out[0] = -acc[0] / (1024.0f * 101.0f);
}

extern "C" void kernel_launch(void* const* d_in, const int* in_sizes, int n_in,
                              void* d_out, int out_size, void* d_ws, size_t ws_size,
                              hipStream_t stream) {
  const float* noise  = (const float*)d_in[0];
  const float* actual = (const float*)d_in[1];
  const int*   target = (const int*)d_in[2];
  float* out = (float*)d_out;
  float* acc = (float*)d_ws;   // 4 bytes of scratch; re-zeroed every launch

  zero_acc_kernel<<<1, 64, 0, stream>>>(acc);
  nce_row_kernel<<<NROWS, 256, 0, stream>>>(noise, actual, target, acc);
  finalize_kernel<<<1, 64, 0, stream>>>(acc, out);
}

// Round 2
// 807.628 us; speedup vs baseline: 1.1272x; 1.1272x over previous
//
#include <hip/hip_runtime.h>
#include <stdint.h>

#define NROWS   1024
#define NV      100000
#define NSEL    101           // K+1
#define NBINS   2048          // 11-bit sortable-float bins
#define POOLSZ  3072          // >= CHUNK + steady-state survivors (no-drop invariant)
#define NTHR    512
#define CHUNK   2048          // 512 threads x 1 float4
#define NCHUNK  ((NV + CHUNK - 1) / CHUNK)   // 49

__device__ __forceinline__ uint32_t rotl32(uint32_t x, uint32_t r) {
  return (x << r) | (x >> (32u - r));
}

// JAX threefry2x32, partitionable path: bits(n) = o0 ^ o1 of
// threefry2x32(key=(0,42), counts=(hi=0, lo=n)). Bit-exact (absmax 0.0 in R1).
__device__ __forceinline__ uint32_t jax_random_bits(uint32_t n) {
  const uint32_t K1 = 42u;
  const uint32_t K2 = 0x1BD11BF0u;
  uint32_t x0 = 0u;
  uint32_t x1 = n + K1;
#define TF_R(r) { x0 += x1; x1 = rotl32(x1, (r)); x1 ^= x0; }
  TF_R(13u) TF_R(15u) TF_R(26u) TF_R(6u)
  x0 += K1; x1 += K2 + 1u;
  TF_R(17u) TF_R(29u) TF_R(16u) TF_R(24u)
  x0 += K2; x1 += 0u + 2u;
  TF_R(13u) TF_R(15u) TF_R(26u) TF_R(6u)
  x0 += 0u; x1 += K1 + 3u;
  TF_R(17u) TF_R(29u) TF_R(16u) TF_R(24u)
  x0 += K1; x1 += K2 + 4u;
  TF_R(13u) TF_R(15u) TF_R(26u) TF_R(6u)
  x0 += K2; x1 += 0u + 5u;
#undef TF_R
  return x0 ^ x1;
}

__device__ __forceinline__ float jax_gumbel(uint32_t n) {
  uint32_t bits = jax_random_bits(n);
  float f = __uint_as_float((bits >> 9) | 0x3f800000u) - 1.0f;
  f = fmaxf(f, 1.1754943508222875e-38f);
  return -__logf(-__logf(f));
}

// reduce across 512 threads; invalid lanes padded with -inf (max) / 0 (sum)
__device__ __forceinline__ float blk_reduce(float x, int tid, float* wred, bool is_max) {
  #pragma unroll
  for (int off = 32; off >= 1; off >>= 1) {
    float o = __shfl_down(x, off);
    x = is_max ? fmaxf(x, o) : (x + o);
  }
  if ((tid & 63) == 0) wred[tid >> 6] = x;
  __syncthreads();
  float r = wred[0];
  #pragma unroll
  for (int w = 1; w < NTHR / 64; ++w)
    r = is_max ? fmaxf(r, wred[w]) : (r + wred[w]);
  __syncthreads();
  return r;
}

__device__ __forceinline__ uint32_t sortable_bin(float v) {
  uint32_t fb = __float_as_uint(v);
  uint32_t key = fb ^ (uint32_t)(((int32_t)fb >> 31) | (int32_t)0x80000000);
  return key >> 21;  // top 11 bits -> 2048 bins, monotone in v
}

__global__ void __launch_bounds__(NTHR, 8)
nce_row_kernel(const float* __restrict__ noise, const float* __restrict__ actual,
               const int* __restrict__ target, float* __restrict__ acc,
               uint32_t* __restrict__ ticket, float* __restrict__ out) {
  const int row = blockIdx.x;
  const int tid = threadIdx.x;
  const int lane = tid & 63;

  __shared__ float    pv[POOLSZ];
  __shared__ uint32_t pi[POOLSZ];
  __shared__ uint32_t hist[NBINS];
  __shared__ uint32_t s_cnt;
  __shared__ uint32_t s_thr;
  __shared__ float    s_wred[NTHR / 64];

  for (int i = tid; i < NBINS; i += NTHR) hist[i] = 0u;
  if (tid == 0) { s_cnt = 0u; s_thr = 0u; }
  __syncthreads();

  const float* rowp = noise + (size_t)row * NV;
  const uint32_t tgt = (uint32_t)target[row];
  const uint32_t nbase = (uint32_t)row * (uint32_t)NV;  // < 2^32

  // software prefetch: chunk c+1's load issued before chunk c's compute+barriers
  float4 a;
  {
    const int v0 = tid * 4;
    if (v0 < NV) a = *reinterpret_cast<const float4*>(rowp + v0);
  }

  for (int c = 0; c < NCHUNK; ++c) {
    float4 a_next;
    {
      const int vn = (c + 1) * CHUNK + tid * 4;
      if (c + 1 < NCHUNK && vn < NV)
        a_next = *reinterpret_cast<const float4*>(rowp + vn);
    }

    const uint32_t thr = s_thr;   // stale-low is safe (over-appends only)
    const int v = c * CHUNK + tid * 4;
    const float av[4] = {a.x, a.y, a.z, a.w};
    #pragma unroll
    for (int j = 0; j < 4; ++j) {
      const uint32_t col = (uint32_t)(v + j);
      const bool valid = (v + j) < NV;
      // masked logit: target -> float32 finfo.min (stays finite after +g)
      const float logit = (col == tgt) ? -3.4028234663852886e+38f : av[j];
      const float val = logit + jax_gumbel(nbase + col);
      const uint32_t bin = sortable_bin(val);
      const bool pred = valid && (bin >= thr);
      // per-wave aggregated append: 1 atomic per wave instead of per lane
      const unsigned long long mask = __ballot(pred);
      if (mask) {
        const int leader = __ffsll((long long)mask) - 1;
        uint32_t base = 0;
        if (lane == leader) base = atomicAdd(&s_cnt, (uint32_t)__popcll(mask));
        base = __shfl(base, leader);
        if (pred) {
          const uint32_t pos = base + (uint32_t)__popcll(mask & ((1ull << lane) - 1ull));
          if (pos < POOLSZ) { pv[pos] = val; pi[pos] = col; }
          atomicAdd(&hist[bin], 1u);
        }
      }
    }
    __syncthreads();

    // wave 0: raise threshold = lowest bin with >=100 seen elements above it
    if (tid < 64) {
      const int bpl = NBINS / 64;           // 32 bins per lane
      uint32_t sum = 0;
      const uint32_t base = (uint32_t)tid * bpl;
      #pragma unroll
      for (int j = 0; j < bpl; ++j) sum += hist[base + j];
      uint32_t suf = sum;
      #pragma unroll
      for (int off = 1; off < 64; off <<= 1) {
        uint32_t o = __shfl_down(suf, off);
        if (tid + off < 64) suf += o;
      }
      const uint32_t sufnext = suf - sum;   // suffix starting at next lane
      if (suf >= 100u && sufnext < 100u) {
        uint32_t cum = sufnext;
        uint32_t b = base + bpl - 1;
        for (;; --b) { cum += hist[b]; if (cum >= 100u) break; }
        if (b > s_thr) s_thr = b;           // single writer lane
      }
    }
    __syncthreads();

    // compact pool when it could overflow next chunk (append <= CHUNK/chunk)
    if (s_cnt > (uint32_t)(POOLSZ - CHUNK)) {
      const uint32_t n = min(s_cnt, (uint32_t)POOLSZ);
      const uint32_t thr2 = s_thr;
      float lv[POOLSZ / NTHR]; uint32_t li[POOLSZ / NTHR]; int nkeep = 0;
      for (uint32_t p = tid; p < n; p += NTHR) {
        float val = pv[p];
        if (sortable_bin(val) >= thr2) { lv[nkeep] = val; li[nkeep] = pi[p]; ++nkeep; }
      }
      __syncthreads();
      if (tid == 0) s_cnt = 0u;
      __syncthreads();
      for (int k = 0; k < nkeep; ++k) {
        uint32_t pos = atomicAdd(&s_cnt, 1u);
        if (pos < POOLSZ) { pv[pos] = lv[k]; pi[pos] = li[k]; }
      }
      __syncthreads();
    }
    a = a_next;
  }
  __syncthreads();

  // ---- final exact top-100, sorted desc by (val, then idx asc) ----
  const uint32_t n = min(s_cnt, (uint32_t)2048);   // realistically ~700 (<=1024+tail)
  uint32_t sortn = 128;
  while (sortn < n) sortn <<= 1;                   // <= 2048
  for (uint32_t i = n + tid; i < sortn; i += NTHR) { pv[i] = -INFINITY; pi[i] = 0xFFFFFFFFu; }
  __syncthreads();

  for (uint32_t ksz = 2; ksz <= sortn; ksz <<= 1) {
    for (uint32_t jsz = ksz >> 1; jsz >= 1; jsz >>= 1) {
      for (uint32_t i = tid; i < sortn; i += NTHR) {
        const uint32_t ixj = i ^ jsz;
        if (ixj > i) {
          const bool desc = ((i & ksz) == 0);
          float va = pv[i], vb = pv[ixj];
          uint32_t ia = pi[i], ib = pi[ixj];
          const bool a_less = (va < vb) || (va == vb && ia > ib);
          if (desc ? a_less : !a_less) {
            pv[i] = vb; pv[ixj] = va; pi[i] = ib; pi[ixj] = ia;
          }
        }
      }
      __syncthreads();
    }
  }

  // ---- scoring: softmax over gathered noise logits & actual logits ----
  float nl = -INFINITY, al = -INFINITY;
  if (tid < NSEL) {
    const uint32_t idx = (tid == 0) ? tgt : pi[tid - 1];
    nl = rowp[idx];                            // original (unmasked) logits
    al = actual[(size_t)row * NSEL + tid];
  }
  const float mn = blk_reduce(nl, tid, s_wred, true);
  const float ma = blk_reduce(al, tid, s_wred, true);
  const float en = (tid < NSEL) ? __expf(nl - mn) : 0.0f;
  const float ea = (tid < NSEL) ? __expf(al - ma) : 0.0f;
  const float sn = blk_reduce(en, tid, s_wred, false);
  const float sa = blk_reduce(ea, tid, s_wred, false);

  float contrib = 0.0f;
  if (tid < NSEL) {
    const float npj = en / sn;
    const float apj = ea / sa;
    const float deno = 100.0f * npj + apj + 1e-6f;
    float t = (tid == 0) ? (apj / deno) : (npj / deno);
    if (t == 1.0f) t = 1.0f + 1e-6f;           // exact reference quirk
    contrib = logf(t);
  }
  const float tot = blk_reduce(contrib, tid, s_wred, false);

  // last-finishing block finalizes (device-scope atomics; acc/ticket pre-zeroed)
  if (tid == 0) {
    atomicAdd(acc, tot);
    __threadfence();
    const uint32_t t = atomicAdd(ticket, 1u);
    if (t == (uint32_t)(NROWS - 1)) {
      const float total = atomicAdd(acc, 0.0f) + 0.0f;  // returns final sum (old value)
      out[0] = -total / (1024.0f * 101.0f);
    }
  }
}

extern "C" void kernel_launch(void* const* d_in, const int* in_sizes, int n_in,
                              void* d_out, int out_size, void* d_ws, size_t ws_size,
                              hipStream_t stream) {
  const float* noise  = (const float*)d_in[0];
  const float* actual = (const float*)d_in[1];
  const int*   target = (const int*)d_in[2];
  float* out = (float*)d_out;
  float*    acc    = (float*)d_ws;
  uint32_t* ticket = (uint32_t*)d_ws + 1;

  hipMemsetAsync(d_ws, 0, 8, stream);   // zero acc + ticket (capture-legal)
  nce_row_kernel<<<NROWS, NTHR, 0, stream>>>(noise, actual, target, acc, ticket, out);
}

// Round 3
// 773.007 us; speedup vs baseline: 1.1777x; 1.0448x over previous
//
#include <hip/hip_runtime.h>
#include <stdint.h>

#define NROWS   1024
#define NV      100000
#define NSEL    101            // K+1
#define NEED    101            // threshold slack: 100 + possibly-unmasked target
#define POOLW   480            // per-wave pool entries
#define NWAVE   8
#define NTHR    512
#define STRIPE  12500          // NV / NWAVE
#define FULLIT  48             // 48*256 = 12288; tail = 212 = 53 lanes * 4

__device__ __forceinline__ uint32_t rotl32(uint32_t x, uint32_t r) {
  return (x << r) | (x >> (32u - r));
}

// JAX threefry2x32, partitionable path: bits(n) = o0 ^ o1 of
// threefry2x32(key=(0,42), counts=(hi=0, lo=n)). Bit-exact (absmax 0.0 R1/R2).
__device__ __forceinline__ uint32_t jax_random_bits(uint32_t n) {
  const uint32_t K1 = 42u;
  const uint32_t K2 = 0x1BD11BF0u;
  uint32_t x0 = 0u;
  uint32_t x1 = n + K1;
#define TF_R(r) { x0 += x1; x1 = rotl32(x1, (r)); x1 ^= x0; }
  TF_R(13u) TF_R(15u) TF_R(26u) TF_R(6u)
  x0 += K1; x1 += K2 + 1u;
  TF_R(17u) TF_R(29u) TF_R(16u) TF_R(24u)
  x0 += K2; x1 += 0u + 2u;
  TF_R(13u) TF_R(15u) TF_R(26u) TF_R(6u)
  x0 += 0u; x1 += K1 + 3u;
  TF_R(17u) TF_R(29u) TF_R(16u) TF_R(24u)
  x0 += K1; x1 += K2 + 4u;
  TF_R(13u) TF_R(15u) TF_R(26u) TF_R(6u)
  x0 += K2; x1 += 0u + 5u;
#undef TF_R
  return x0 ^ x1;
}

__device__ __forceinline__ float blk_reduce(float x, int tid, float* wred, bool is_max) {
  #pragma unroll
  for (int off = 32; off >= 1; off >>= 1) {
    float o = __shfl_down(x, off);
    x = is_max ? fmaxf(x, o) : (x + o);
  }
  if ((tid & 63) == 0) wred[tid >> 6] = x;
  __syncthreads();
  float r = wred[0];
  #pragma unroll
  for (int w = 1; w < NTHR / 64; ++w)
    r = is_max ? fmaxf(r, wred[w]) : (r + wred[w]);
  __syncthreads();
  return r;
}

// bin b lives at phys ((b&31)<<6)|(b>>5): scan reads are stride-64 (2-way, free)
__device__ __forceinline__ uint32_t hist_phys(uint32_t b) {
  return ((b & 31u) << 6) | (b >> 5);
}

// smallest real float f with sortable_key(f) >= (b<<21); pred (val>=f) <=> bin(val)>=b
__device__ __forceinline__ float binlow_float(uint32_t b) {
  uint32_t k = b << 21;
  if (k & 0x80000000u) {
    uint32_t fb = k ^ 0x80000000u;
    return (fb >= 0x7F800000u) ? INFINITY : __uint_as_float(fb);
  } else {
    uint32_t fb = ~k;
    return (fb >= 0xFF800000u) ? -INFINITY : __uint_as_float(fb);
  }
}

// wave-local scan of shared hist: highest bin b with suffix-count >= need, else -1.
// Racy reads are safe: counts only grow, so any read <= true count.
__device__ __forceinline__ int wave_scan_thr(volatile uint32_t* hist, int lane, uint32_t need) {
  uint32_t sum = 0;
  #pragma unroll
  for (int j = 0; j < 32; ++j) sum += hist[(j << 6) | lane];
  uint32_t suf = sum;
  #pragma unroll
  for (int off = 1; off < 64; off <<= 1) {
    uint32_t o = __shfl_down(suf, off);
    if (lane + off < 64) suf += o;
  }
  const uint32_t sufnext = suf - sum;
  int b = -1;
  if (suf >= need && sufnext < need) {
    uint32_t cum = sufnext;
    int j = 31;
    for (;; --j) {
      cum += hist[(j << 6) | lane];
      if (cum >= need || j == 0) break;
    }
    b = lane * 32 + j;
  }
  #pragma unroll
  for (int off = 32; off >= 1; off >>= 1) b = max(b, __shfl_xor(b, off));
  return b;
}

// monotone raise of shared threshold; out-of-order thrf writes are stale-LOW -> safe
__device__ __forceinline__ void raise_thr(int b, int lane, uint32_t* thrkey, volatile float* thrf) {
  if (b < 0) return;
  if (lane == 0) {
    uint32_t old = atomicMax(thrkey, (uint32_t)b);
    if ((uint32_t)b > old) *thrf = binlow_float((uint32_t)b);
  }
}

// one element: threefry + clz-prefilter; full gumbel only if any lane might pass.
// Bound: g = -ln(-ln u) <= -ln(1-u) <= (clz(2^23 - u23) - 8)*ln2  (since -ln u >= 1-u).
__device__ __forceinline__ void proc_elem(
    float logit, uint32_t n, uint32_t col, float thrf, float thr_s, int lane,
    float* pv_w, uint32_t* pi_w, uint32_t* hist, uint32_t& cnt) {
  const uint32_t bits = jax_random_bits(n);
  const uint32_t b23 = bits >> 9;
  const uint32_t m = 0x800000u - b23;                 // in [1, 2^23]
  const float clzf = (float)__clz((int)m);
  // skip if clz < (thrf - logit)/ln2 + 8;  thr_s = thrf/ln2 + 8 (wave-uniform)
  const float req = fmaf(logit, -1.4426950408889634f, thr_s);
  const bool maybe = (clzf >= req);                   // NaN logit => false
  if (__ballot(maybe) == 0ull) return;
  float f1 = __uint_as_float(b23 | 0x3f800000u) - 1.0f;
  float u = fmaxf(f1, 1.1754943508222875e-38f);
  const float g = -__logf(-__logf(u));                // exact R1 gumbel
  const float val = logit + g;
  const bool pred = maybe && (val >= thrf);
  const unsigned long long mk = __ballot(pred);
  if (mk == 0ull) return;
  const uint32_t pos = cnt + (uint32_t)__popcll(mk & ((1ull << lane) - 1ull));
  if (pred && pos < (uint32_t)POOLW) {
    pv_w[pos] = val;
    pi_w[pos] = col;
    uint32_t fb = __float_as_uint(val);
    uint32_t key = fb ^ (uint32_t)(((int32_t)fb >> 31) | (int32_t)0x80000000);
    atomicAdd(&hist[hist_phys(key >> 21)], 1u);       // hist counts stored elems only
  }
  cnt += (uint32_t)__popcll(mk);
}

__global__ void __launch_bounds__(NTHR, 8)
nce_row_kernel(const float* __restrict__ noise, const float* __restrict__ actual,
               const int* __restrict__ target, float* __restrict__ acc,
               uint32_t* __restrict__ ticket, float* __restrict__ out) {
  const int row = blockIdx.x;
  const int tid = threadIdx.x;
  const int lane = tid & 63;
  const uint32_t w = (uint32_t)tid >> 6;

  __shared__ float    pv[NWAVE * POOLW];
  __shared__ uint32_t pi_[NWAVE * POOLW];
  __shared__ uint32_t uni[2048];        // hist during stream; mv/mi at merge
  __shared__ uint32_t s_cnt[NWAVE];
  __shared__ uint32_t s_thrkey;
  __shared__ float    s_thrf;
  __shared__ float    s_thrf_final;
  __shared__ uint32_t s_mcnt;
  __shared__ float    s_wred[NTHR / 64];

  uint32_t* hist = uni;
  float*    mv   = (float*)uni;         // [0..1023]   (reused after final scan)
  uint32_t* mi   = uni + 1024;          // [0..1023]

  for (int i = tid; i < 2048; i += NTHR) hist[i] = 0u;
  if (tid == 0) { s_thrkey = 0u; s_thrf = -INFINITY; s_mcnt = 0u; }
  __syncthreads();

  const float* rowp = noise + (size_t)row * NV;
  const uint32_t tgt = (uint32_t)target[row];
  const uint32_t nbase = (uint32_t)row * (uint32_t)NV;
  const uint32_t stripe0 = w * (uint32_t)STRIPE;
  const float* sp = rowp + stripe0;
  float*    pv_w = pv  + w * POOLW;
  uint32_t* pi_w = pi_ + w * POOLW;
  volatile float* vthrf = &s_thrf;

  uint32_t cnt = 0;
  const float qnan = __int_as_float(0x7fc00000);

  float4 a = *reinterpret_cast<const float4*>(sp + lane * 4);

  for (int it = 0; it < FULLIT; ++it) {
    float4 an;
    if (it < FULLIT - 1) {
      an = *reinterpret_cast<const float4*>(sp + (it + 1) * 256 + lane * 4);
    } else if (lane < 53) {
      an = *reinterpret_cast<const float4*>(sp + FULLIT * 256 + lane * 4);
    }

    const float thrf = *vthrf;                        // monotone, stale-low safe
    const float thr_s = fmaf(thrf, 1.4426950408889634f, 8.0f);
    const uint32_t e0 = stripe0 + (uint32_t)(it * 256 + lane * 4);
    proc_elem(a.x, nbase + e0 + 0u, e0 + 0u, thrf, thr_s, lane, pv_w, pi_w, hist, cnt);
    proc_elem(a.y, nbase + e0 + 1u, e0 + 1u, thrf, thr_s, lane, pv_w, pi_w, hist, cnt);
    proc_elem(a.z, nbase + e0 + 2u, e0 + 2u, thrf, thr_s, lane, pv_w, pi_w, hist, cnt);
    proc_elem(a.w, nbase + e0 + 3u, e0 + 3u, thrf, thr_s, lane, pv_w, pi_w, hist, cnt);

    if (cnt > (uint32_t)(POOLW - 256)) {
      // compact: raise thr from hist, then refilter own pool in place
      int b = wave_scan_thr(hist, lane, NEED);
      raise_thr(b, lane, &s_thrkey, vthrf);
      const float tf = *vthrf;
      const uint32_t n0 = min(cnt, (uint32_t)POOLW);
      uint32_t nc = 0;
      for (uint32_t p0 = 0; p0 < n0; p0 += 64) {
        const uint32_t p = p0 + (uint32_t)lane;
        const bool v = (p < n0);
        float vv = 0.0f; uint32_t ii = 0;
        if (v) { vv = pv_w[p]; ii = pi_w[p]; }
        const bool keep = v && (vv >= tf);
        const unsigned long long km = __ballot(keep);
        const uint32_t np = nc + (uint32_t)__popcll(km & ((1ull << lane) - 1ull));
        if (keep) { pv_w[np] = vv; pi_w[np] = ii; }
        nc += (uint32_t)__popcll(km);
      }
      cnt = nc;
    } else if ((it & 15) == 7) {
      int b = wave_scan_thr(hist, lane, NEED);
      raise_thr(b, lane, &s_thrkey, vthrf);
    }
    a = an;
  }

  { // tail: 212 elements = 53 lanes x 4; invalid lanes get NaN logits (fail prefilter)
    const float thrf = *vthrf;
    const float thr_s = fmaf(thrf, 1.4426950408889634f, 8.0f);
    const uint32_t e0 = stripe0 + (uint32_t)(FULLIT * 256 + lane * 4);
    const bool lv = (lane < 53);
    proc_elem(lv ? a.x : qnan, nbase + e0 + 0u, e0 + 0u, thrf, thr_s, lane, pv_w, pi_w, hist, cnt);
    proc_elem(lv ? a.y : qnan, nbase + e0 + 1u, e0 + 1u, thrf, thr_s, lane, pv_w, pi_w, hist, cnt);
    proc_elem(lv ? a.z : qnan, nbase + e0 + 2u, e0 + 2u, thrf, thr_s, lane, pv_w, pi_w, hist, cnt);
    proc_elem(lv ? a.w : qnan, nbase + e0 + 3u, e0 + 3u, thrf, thr_s, lane, pv_w, pi_w, hist, cnt);
  }

  if (lane == 0) s_cnt[w] = min(cnt, (uint32_t)POOLW);
  __syncthreads();

  // exact final threshold from complete hist (wave 0)
  if (tid < 64) {
    int b = wave_scan_thr(hist, lane, NEED);          // b >= 0 guaranteed (hist >= NEED)
    if (lane == 0) s_thrf_final = binlow_float((uint32_t)(b < 0 ? 0 : b));
  }
  __syncthreads();
  const float tf = s_thrf_final;

  // merge-compact all pools' entries >= tf (excluding target) into mv/mi (aliases hist)
  for (uint32_t s = tid; s < (uint32_t)(NWAVE * POOLW); s += NTHR) {
    const uint32_t wq = s / POOLW;
    const uint32_t p = s - wq * POOLW;
    bool keep = (p < s_cnt[wq]);
    float vv = 0.0f; uint32_t ii = 0;
    if (keep) {
      vv = pv[s]; ii = pi_[s];
      keep = (vv >= tf) && (ii != tgt);
    }
    const unsigned long long km = __ballot(keep);
    const uint32_t nb = (uint32_t)__popcll(km);
    if (nb) {
      uint32_t base = 0;
      if (lane == 0) base = atomicAdd(&s_mcnt, nb);
      base = __shfl(base, 0);
      if (keep) {
        const uint32_t pos = base + (uint32_t)__popcll(km & ((1ull << lane) - 1ull));
        if (pos < 1024u) { mv[pos] = vv; mi[pos] = ii; }
      }
    }
  }
  __syncthreads();
  const uint32_t mc = min(s_mcnt, 1024u);
  for (uint32_t i = mc + tid; i < 1024u; i += NTHR) { mv[i] = -INFINITY; mi[i] = 0xFFFFFFFFu; }
  __syncthreads();

  // bitonic sort 1024 desc by (val, idx asc) — matches lax.top_k tie-breaking
  for (uint32_t ksz = 2; ksz <= 1024u; ksz <<= 1) {
    for (uint32_t jsz = ksz >> 1; jsz >= 1; jsz >>= 1) {
      for (uint32_t i = tid; i < 1024u; i += NTHR) {
        const uint32_t ixj = i ^ jsz;
        if (ixj > i) {
          const bool desc = ((i & ksz) == 0);
          float va = mv[i], vb = mv[ixj];
          uint32_t ia = mi[i], ib = mi[ixj];
          const bool a_less = (va < vb) || (va == vb && ia > ib);
          if (desc ? a_less : !a_less) {
            mv[i] = vb; mv[ixj] = va; mi[i] = ib; mi[ixj] = ia;
          }
        }
      }
      __syncthreads();
    }
  }

  // scoring: softmax over gathered noise logits & actual logits
  float nl = -INFINITY, al = -INFINITY;
  if (tid < NSEL) {
    const uint32_t idx = (tid == 0) ? tgt : mi[tid - 1];
    nl = rowp[idx];                            // original (unmasked) logits
    al = actual[(size_t)row * NSEL + tid];
  }
  const float mn = blk_reduce(nl, tid, s_wred, true);
  const float ma = blk_reduce(al, tid, s_wred, true);
  const float en = (tid < NSEL) ? __expf(nl - mn) : 0.0f;
  const float ea = (tid < NSEL) ? __expf(al - ma) : 0.0f;
  const float sn = blk_reduce(en, tid, s_wred, false);
  const float sa = blk_reduce(ea, tid, s_wred, false);

  float contrib = 0.0f;
  if (tid < NSEL) {
    const float npj = en / sn;
    const float apj = ea / sa;
    const float deno = 100.0f * npj + apj + 1e-6f;
    float t = (tid == 0) ? (apj / deno) : (npj / deno);
    if (t == 1.0f) t = 1.0f + 1e-6f;           // exact reference quirk
    contrib = logf(t);
  }
  const float tot = blk_reduce(contrib, tid, s_wred, false);

  if (tid == 0) {
    atomicAdd(acc, tot);
    __threadfence();
    const uint32_t tk = atomicAdd(ticket, 1u);
    if (tk == (uint32_t)(NROWS - 1)) {
      const float total = atomicAdd(acc, 0.0f);
      out[0] = -total / (1024.0f * 101.0f);
    }
  }
}

extern "C" void kernel_launch(void* const* d_in, const int* in_sizes, int n_in,
                              void* d_out, int out_size, void* d_ws, size_t ws_size,
                              hipStream_t stream) {
  const float* noise  = (const float*)d_in[0];
  const float* actual = (const float*)d_in[1];
  const int*   target = (const int*)d_in[2];
  float* out = (float*)d_out;
  float*    acc    = (float*)d_ws;
  uint32_t* ticket = (uint32_t*)d_ws + 1;

  hipMemsetAsync(d_ws, 0, 8, stream);
  nce_row_kernel<<<NROWS, NTHR, 0, stream>>>(noise, actual, target, acc, ticket, out);
}